// Round 2
// baseline (1338.608 us; speedup 1.0000x reference)
//
#include <hip/hip_runtime.h>
#include <hip/hip_bf16.h>
#include <cstdint>
#include <cstddef>

#define HIDDEN 2048
#define INTER 8192
#define M_TOK 8192   // BATCH * LOCAL_SEQ = 2 * 4096

typedef __attribute__((ext_vector_type(8))) short short8;   // 8 bf16 = 4 VGPRs
typedef __attribute__((ext_vector_type(4))) float float4v;  // MFMA C/D

typedef __hip_bfloat16 bf16;

// ---------------------------------------------------------------------------
// fp32 -> bf16 convert (memory-bound, grid-stride)
// ---------------------------------------------------------------------------
__global__ void cvt_bf16(const float* __restrict__ src, bf16* __restrict__ dst, int n) {
    int idx = blockIdx.x * blockDim.x + threadIdx.x;
    int stride = gridDim.x * blockDim.x;
    for (int i = idx * 4; i < n; i += stride * 4) {
        float4 v = *(const float4*)(src + i);
        union { bf16 h[4]; ushort4 u; } pk;
        pk.h[0] = __float2bfloat16(v.x);
        pk.h[1] = __float2bfloat16(v.y);
        pk.h[2] = __float2bfloat16(v.z);
        pk.h[3] = __float2bfloat16(v.w);
        *(ushort4*)(dst + i) = pk.u;
    }
}

// out += partial (fp32, float4)
__global__ void add_partial(float* __restrict__ out, const float* __restrict__ p, int n) {
    int i = (blockIdx.x * blockDim.x + threadIdx.x) * 4;
    if (i < n) {
        float4 a = *(const float4*)(out + i);
        float4 b = *(const float4*)(p + i);
        a.x += b.x; a.y += b.y; a.z += b.z; a.w += b.w;
        *(float4*)(out + i) = a;
    }
}

// async global->LDS, 16B per lane; LDS dest = wave-uniform base + lane*16
__device__ __forceinline__ void load16_lds(const void* g, void* l) {
    __builtin_amdgcn_global_load_lds((const __attribute__((address_space(1))) void*)g,
                                     (__attribute__((address_space(3))) void*)l,
                                     16, 0, 0);
}

// XOR-swizzle scheme (kills ds_read_b128 bank conflicts, m136 math):
//   LDS tile row r (64 B = 4 slots of 16 B). Slot s holds global k-chunk
//   s ^ ((r>>1)&3). Staged by permuting the GLOBAL source per lane (the
//   global_load_lds lane->LDS mapping is fixed). Fragment read for row r,
//   k-group kg reads slot kg ^ ((r>>1)&3); since all fragment rows are
//   lm mod 16, the XOR key (lm>>1)&3 is loop-invariant per lane.

// ---------------------------------------------------------------------------
// GEMM1 + SiLU fusion.
//   A = h_bf16 [8192][2048], B = w_gate_up [16384][2048] (NT), act bf16 [8192][8192]
//   Block: 128 tokens x (64 gate + 64 up cols). acc j=0,1 gate, j=2,3 up,
//   identical C/D lane mapping -> lane-local silu.
// ---------------------------------------------------------------------------
__global__ __launch_bounds__(256) void gemm1_act(const bf16* __restrict__ A,
                                                 const bf16* __restrict__ B,
                                                 bf16* __restrict__ act) {
    __shared__ __align__(16) bf16 lA[128 * 32];   // 8 KB
    __shared__ __align__(16) bf16 lB[128 * 32];   // 8 KB: rows 0..63 gate, 64..127 up

    const int tid  = threadIdx.x;
    const int wave = tid >> 6;
    const int lane = tid & 63;
    const int m0 = blockIdx.y * 128;
    const int n0 = blockIdx.x * 64;

    const int wm = wave >> 1, wn = wave & 1;
    const int lm = lane & 15;          // fragment row/col within 16
    const int kg = lane >> 4;          // k-group 0..3
    const int srow = lane >> 2;        // staging: row within 16-row chunk
    // swizzled source k-chunk for staging: (slot)^((srow>>1)&3)
    const int scol = (((lane & 3) ^ ((lane >> 3) & 3)) * 8);
    const int fsw  = (kg ^ ((lm >> 1) & 3)) * 8;   // fragment-read slot offset (elements)

    float4v acc[4][4];
#pragma unroll
    for (int i = 0; i < 4; i++)
#pragma unroll
        for (int j = 0; j < 4; j++) acc[i][j] = (float4v)0.f;

    for (int k0 = 0; k0 < HIDDEN; k0 += 32) {
#pragma unroll
        for (int it = 0; it < 2; ++it) {
            const int c = wave * 2 + it;
            const int row = c * 16 + srow;                  // 0..127
            const bf16* ga = A + (size_t)(m0 + row) * HIDDEN + k0 + scol;
            load16_lds(ga, lA + c * 512);
            const int brow = (row < 64) ? (n0 + row) : (INTER + n0 + row - 64);
            const bf16* gb = B + (size_t)brow * HIDDEN + k0 + scol;
            load16_lds(gb, lB + c * 512);
        }
        __syncthreads();

        short8 bfr[4];
#pragma unroll
        for (int j = 0; j < 4; j++) {
            const int r = ((j < 2) ? 0 : 64) + wn * 32 + (j & 1) * 16 + lm;
            bfr[j] = *(const short8*)(lB + r * 32 + fsw);
        }
#pragma unroll
        for (int i = 0; i < 4; i++) {
            const int r = wm * 64 + i * 16 + lm;
            const short8 afr = *(const short8*)(lA + r * 32 + fsw);
#pragma unroll
            for (int j = 0; j < 4; j++)
                acc[i][j] = __builtin_amdgcn_mfma_f32_16x16x32_bf16(afr, bfr[j], acc[i][j], 0, 0, 0);
        }
        __syncthreads();
    }

    // epilogue: act = silu(gate) * up; C/D layout col=lane&15, row=(lane>>4)*4+reg
    const int orow = m0 + wm * 64;
    const int ocol = n0 + wn * 32;
#pragma unroll
    for (int i = 0; i < 4; i++)
#pragma unroll
        for (int j = 0; j < 2; j++)
#pragma unroll
            for (int r = 0; r < 4; r++) {
                const float g = acc[i][j][r];
                const float u = acc[i][j + 2][r];
                const float a = (g / (1.f + __expf(-g))) * u;
                const int row = orow + i * 16 + kg * 4 + r;
                const int col = ocol + j * 16 + lm;
                act[(size_t)row * INTER + col] = __float2bfloat16(a);
            }
}

// ---------------------------------------------------------------------------
// GEMM2 split-K=2: out = act @ w_down^T.
//   A = act [8192][8192] bf16, B = w_down [2048][8192] bf16 (NT), C fp32.
//   grid (16, 64, 2): z=0 -> C0 (d_out) with K [0,4096), z=1 -> C1 (ws partial)
//   with K [4096,8192). Single launch so both halves co-schedule (same-stream
//   launches serialize; 1024-block grid had 33% tail waste at 3 blocks/CU).
// ---------------------------------------------------------------------------
__global__ __launch_bounds__(256) void gemm2(const bf16* __restrict__ A,
                                             const bf16* __restrict__ B,
                                             float* __restrict__ C0,
                                             float* __restrict__ C1) {
    __shared__ __align__(16) bf16 lA[128 * 32];
    __shared__ __align__(16) bf16 lB[128 * 32];

    const int tid  = threadIdx.x;
    const int wave = tid >> 6;
    const int lane = tid & 63;
    const int m0 = blockIdx.y * 128;
    const int n0 = blockIdx.x * 128;
    float* __restrict__ C = (blockIdx.z == 0) ? C0 : C1;
    const int kbase = blockIdx.z * (INTER / 2);

    const int wm = wave >> 1, wn = wave & 1;
    const int lm = lane & 15;
    const int kg = lane >> 4;
    const int srow = lane >> 2;
    const int scol = (((lane & 3) ^ ((lane >> 3) & 3)) * 8);
    const int fsw  = (kg ^ ((lm >> 1) & 3)) * 8;

    float4v acc[4][4];
#pragma unroll
    for (int i = 0; i < 4; i++)
#pragma unroll
        for (int j = 0; j < 4; j++) acc[i][j] = (float4v)0.f;

    for (int k0 = kbase; k0 < kbase + INTER / 2; k0 += 32) {
#pragma unroll
        for (int it = 0; it < 2; ++it) {
            const int c = wave * 2 + it;
            const int row = c * 16 + srow;
            const bf16* ga = A + (size_t)(m0 + row) * INTER + k0 + scol;
            load16_lds(ga, lA + c * 512);
            const bf16* gb = B + (size_t)(n0 + row) * INTER + k0 + scol;
            load16_lds(gb, lB + c * 512);
        }
        __syncthreads();

        short8 bfr[4];
#pragma unroll
        for (int j = 0; j < 4; j++) {
            const int r = wn * 64 + j * 16 + lm;
            bfr[j] = *(const short8*)(lB + r * 32 + fsw);
        }
#pragma unroll
        for (int i = 0; i < 4; i++) {
            const int r = wm * 64 + i * 16 + lm;
            const short8 afr = *(const short8*)(lA + r * 32 + fsw);
#pragma unroll
            for (int j = 0; j < 4; j++)
                acc[i][j] = __builtin_amdgcn_mfma_f32_16x16x32_bf16(afr, bfr[j], acc[i][j], 0, 0, 0);
        }
        __syncthreads();
    }

    const int orow = m0 + wm * 64;
    const int ocol = n0 + wn * 64;
#pragma unroll
    for (int i = 0; i < 4; i++)
#pragma unroll
        for (int j = 0; j < 4; j++)
#pragma unroll
            for (int r = 0; r < 4; r++) {
                const int row = orow + i * 16 + kg * 4 + r;
                const int col = ocol + j * 16 + lm;
                C[(size_t)row * HIDDEN + col] = acc[i][j][r];
            }
}

// ---------------------------------------------------------------------------
extern "C" void kernel_launch(void* const* d_in, const int* in_sizes, int n_in,
                              void* d_out, int out_size, void* d_ws, size_t ws_size,
                              hipStream_t stream) {
    const float* h   = (const float*)d_in[0];   // [2,4096,2048]
    const float* wgu = (const float*)d_in[1];   // [16384,2048]
    const float* wd  = (const float*)d_in[2];   // [2048,8192]
    float* out = (float*)d_out;                 // [2,4096,2048]

    char* ws = (char*)d_ws;
    bf16*  hbf     = (bf16*)(ws);                       //  33,554,432 B  [dead after gemm1]
    bf16*  wgubf   = (bf16*)(ws + 33554432ull);         //  67,108,864 B  [dead after gemm1]
    bf16*  wdbf    = (bf16*)(ws + 100663296ull);        //  33,554,432 B
    bf16*  actbf   = (bf16*)(ws + 134217728ull);        // 134,217,728 B
    float* partial = (float*)(ws);                      //  67,108,864 B overlay on hbf/wgubf

    cvt_bf16<<<dim3(4096), 256, 0, stream>>>(h,   hbf,   M_TOK * HIDDEN);
    cvt_bf16<<<dim3(8192), 256, 0, stream>>>(wgu, wgubf, 2 * INTER * HIDDEN);
    cvt_bf16<<<dim3(4096), 256, 0, stream>>>(wd,  wdbf,  HIDDEN * INTER);

    // GEMM1+silu: grid x = INTER/64 = 128 column blocks, y = M_TOK/128 = 64 row blocks
    gemm1_act<<<dim3(128, 64), 256, 0, stream>>>(hbf, wgubf, actbf);

    // GEMM2 split-K=2: z=0 -> out (K first half), z=1 -> partial (K second half)
    gemm2<<<dim3(16, 64, 2), 256, 0, stream>>>(actbf, wdbf, out, partial);

    // out += partial
    add_partial<<<dim3((M_TOK * HIDDEN / 4 + 255) / 256), 256, 0, stream>>>(out, partial, M_TOK * HIDDEN);
}

// Round 3
// 1306.328 us; speedup vs baseline: 1.0247x; 1.0247x over previous
//
#include <hip/hip_runtime.h>
#include <hip/hip_bf16.h>
#include <cstdint>
#include <cstddef>

#define HIDDEN 2048
#define INTER 8192
#define M_TOK 8192   // BATCH * LOCAL_SEQ = 2 * 4096

typedef __attribute__((ext_vector_type(8))) short short8;   // 8 bf16 = 4 VGPRs
typedef __attribute__((ext_vector_type(4))) float float4v;  // MFMA C/D

typedef __hip_bfloat16 bf16;

// ---------------------------------------------------------------------------
// fp32 -> bf16 convert (memory-bound, grid-stride)
// ---------------------------------------------------------------------------
__global__ void cvt_bf16(const float* __restrict__ src, bf16* __restrict__ dst, int n) {
    int idx = blockIdx.x * blockDim.x + threadIdx.x;
    int stride = gridDim.x * blockDim.x;
    for (int i = idx * 4; i < n; i += stride * 4) {
        float4 v = *(const float4*)(src + i);
        union { bf16 h[4]; ushort4 u; } pk;
        pk.h[0] = __float2bfloat16(v.x);
        pk.h[1] = __float2bfloat16(v.y);
        pk.h[2] = __float2bfloat16(v.z);
        pk.h[3] = __float2bfloat16(v.w);
        *(ushort4*)(dst + i) = pk.u;
    }
}

// out += partial (fp32, float4)
__global__ void add_partial(float* __restrict__ out, const float* __restrict__ p, int n) {
    int i = (blockIdx.x * blockDim.x + threadIdx.x) * 4;
    if (i < n) {
        float4 a = *(const float4*)(out + i);
        float4 b = *(const float4*)(p + i);
        a.x += b.x; a.y += b.y; a.z += b.z; a.w += b.w;
        *(float4*)(out + i) = a;
    }
}

// async global->LDS, 16B per lane; LDS dest = wave-uniform base + lane*16
__device__ __forceinline__ void load16_lds(const void* g, void* l) {
    __builtin_amdgcn_global_load_lds((const __attribute__((address_space(1))) void*)g,
                                     (__attribute__((address_space(3))) void*)l,
                                     16, 0, 0);
}

// XOR-swizzle (verified R2: SQ_LDS_BANK_CONFLICT 6.7e7 -> 0):
//   LDS row r = 4 slots of 16 B; slot s holds global k-chunk s ^ ((r>>1)&3),
//   staged by permuting the GLOBAL source per lane. Fragment read uses slot
//   kg ^ ((lm>>1)&3) - loop-invariant per lane.

// ---------------------------------------------------------------------------
// GEMM1 + SiLU fusion.
//   A = h_bf16 [8192][2048], B = w_gate_up [16384][2048] (NT), act bf16 [8192][8192]
//   Block: 128 tokens x (64 gate + 64 up cols). acc j=0,1 gate, j=2,3 up,
//   identical C/D lane mapping -> lane-local silu.
//   __launch_bounds__(256,4): force regs <= 128/thread -> 4 blocks/CU
//   (8192 blocks / 1024 co-resident = 8 exact rounds, + extra waves to
//   overlap the barrier vmcnt drain).
// ---------------------------------------------------------------------------
__global__ __launch_bounds__(256, 4) void gemm1_act(const bf16* __restrict__ A,
                                                    const bf16* __restrict__ B,
                                                    bf16* __restrict__ act) {
    __shared__ __align__(16) bf16 lA[128 * 32];   // 8 KB
    __shared__ __align__(16) bf16 lB[128 * 32];   // 8 KB: rows 0..63 gate, 64..127 up

    const int tid  = threadIdx.x;
    const int wave = tid >> 6;
    const int lane = tid & 63;
    const int m0 = blockIdx.y * 128;
    const int n0 = blockIdx.x * 64;

    const int wm = wave >> 1, wn = wave & 1;
    const int lm = lane & 15;          // fragment row/col within 16
    const int kg = lane >> 4;          // k-group 0..3
    const int srow = lane >> 2;        // staging: row within 16-row chunk
    const int scol = (((lane & 3) ^ ((lane >> 3) & 3)) * 8);  // swizzled source chunk
    const int fsw  = (kg ^ ((lm >> 1) & 3)) * 8;              // fragment-read slot

    float4v acc[4][4];
#pragma unroll
    for (int i = 0; i < 4; i++)
#pragma unroll
        for (int j = 0; j < 4; j++) acc[i][j] = (float4v)0.f;

    for (int k0 = 0; k0 < HIDDEN; k0 += 32) {
#pragma unroll
        for (int it = 0; it < 2; ++it) {
            const int c = wave * 2 + it;
            const int row = c * 16 + srow;                  // 0..127
            const bf16* ga = A + (size_t)(m0 + row) * HIDDEN + k0 + scol;
            load16_lds(ga, lA + c * 512);
            const int brow = (row < 64) ? (n0 + row) : (INTER + n0 + row - 64);
            const bf16* gb = B + (size_t)brow * HIDDEN + k0 + scol;
            load16_lds(gb, lB + c * 512);
        }
        __syncthreads();

        short8 bfr[4];
#pragma unroll
        for (int j = 0; j < 4; j++) {
            const int r = ((j < 2) ? 0 : 64) + wn * 32 + (j & 1) * 16 + lm;
            bfr[j] = *(const short8*)(lB + r * 32 + fsw);
        }
#pragma unroll
        for (int i = 0; i < 4; i++) {
            const int r = wm * 64 + i * 16 + lm;
            const short8 afr = *(const short8*)(lA + r * 32 + fsw);
#pragma unroll
            for (int j = 0; j < 4; j++)
                acc[i][j] = __builtin_amdgcn_mfma_f32_16x16x32_bf16(afr, bfr[j], acc[i][j], 0, 0, 0);
        }
        __syncthreads();
    }

    // epilogue: act = silu(gate) * up; C/D layout col=lane&15, row=(lane>>4)*4+reg
    const int orow = m0 + wm * 64;
    const int ocol = n0 + wn * 32;
#pragma unroll
    for (int i = 0; i < 4; i++)
#pragma unroll
        for (int j = 0; j < 2; j++)
#pragma unroll
            for (int r = 0; r < 4; r++) {
                const float g = acc[i][j][r];
                const float u = acc[i][j + 2][r];
                const float a = (g / (1.f + __expf(-g))) * u;
                const int row = orow + i * 16 + kg * 4 + r;
                const int col = ocol + j * 16 + lm;
                act[(size_t)row * INTER + col] = __float2bfloat16(a);
            }
}

// ---------------------------------------------------------------------------
// GEMM2 split-K=2, INTERLEAVED on x (R2 lesson: z dispatches last -> split
// halves serialized; x is the fastest-varying dispatch dim).
//   grid (32, 64): bx&1 = K-half, bx>>1 = N-block.
//   A = act [8192][8192] bf16, B = w_down [2048][8192] bf16 (NT), C fp32.
// ---------------------------------------------------------------------------
__global__ __launch_bounds__(256, 4) void gemm2(const bf16* __restrict__ A,
                                                const bf16* __restrict__ B,
                                                float* __restrict__ C0,
                                                float* __restrict__ C1) {
    __shared__ __align__(16) bf16 lA[128 * 32];
    __shared__ __align__(16) bf16 lB[128 * 32];

    const int tid  = threadIdx.x;
    const int wave = tid >> 6;
    const int lane = tid & 63;
    const int kz   = blockIdx.x & 1;
    const int m0 = blockIdx.y * 128;
    const int n0 = (blockIdx.x >> 1) * 128;
    float* __restrict__ C = (kz == 0) ? C0 : C1;
    const int kbase = kz * (INTER / 2);

    const int wm = wave >> 1, wn = wave & 1;
    const int lm = lane & 15;
    const int kg = lane >> 4;
    const int srow = lane >> 2;
    const int scol = (((lane & 3) ^ ((lane >> 3) & 3)) * 8);
    const int fsw  = (kg ^ ((lm >> 1) & 3)) * 8;

    float4v acc[4][4];
#pragma unroll
    for (int i = 0; i < 4; i++)
#pragma unroll
        for (int j = 0; j < 4; j++) acc[i][j] = (float4v)0.f;

    for (int k0 = kbase; k0 < kbase + INTER / 2; k0 += 32) {
#pragma unroll
        for (int it = 0; it < 2; ++it) {
            const int c = wave * 2 + it;
            const int row = c * 16 + srow;
            const bf16* ga = A + (size_t)(m0 + row) * INTER + k0 + scol;
            load16_lds(ga, lA + c * 512);
            const bf16* gb = B + (size_t)(n0 + row) * INTER + k0 + scol;
            load16_lds(gb, lB + c * 512);
        }
        __syncthreads();

        short8 bfr[4];
#pragma unroll
        for (int j = 0; j < 4; j++) {
            const int r = wn * 64 + j * 16 + lm;
            bfr[j] = *(const short8*)(lB + r * 32 + fsw);
        }
#pragma unroll
        for (int i = 0; i < 4; i++) {
            const int r = wm * 64 + i * 16 + lm;
            const short8 afr = *(const short8*)(lA + r * 32 + fsw);
#pragma unroll
            for (int j = 0; j < 4; j++)
                acc[i][j] = __builtin_amdgcn_mfma_f32_16x16x32_bf16(afr, bfr[j], acc[i][j], 0, 0, 0);
        }
        __syncthreads();
    }

    const int orow = m0 + wm * 64;
    const int ocol = n0 + wn * 64;
#pragma unroll
    for (int i = 0; i < 4; i++)
#pragma unroll
        for (int j = 0; j < 4; j++)
#pragma unroll
            for (int r = 0; r < 4; r++) {
                const int row = orow + i * 16 + kg * 4 + r;
                const int col = ocol + j * 16 + lm;
                C[(size_t)row * HIDDEN + col] = acc[i][j][r];
            }
}

// ---------------------------------------------------------------------------
extern "C" void kernel_launch(void* const* d_in, const int* in_sizes, int n_in,
                              void* d_out, int out_size, void* d_ws, size_t ws_size,
                              hipStream_t stream) {
    const float* h   = (const float*)d_in[0];   // [2,4096,2048]
    const float* wgu = (const float*)d_in[1];   // [16384,2048]
    const float* wd  = (const float*)d_in[2];   // [2048,8192]
    float* out = (float*)d_out;                 // [2,4096,2048]

    char* ws = (char*)d_ws;
    bf16*  hbf     = (bf16*)(ws);                       //  33,554,432 B  [dead after gemm1]
    bf16*  wgubf   = (bf16*)(ws + 33554432ull);         //  67,108,864 B  [dead after gemm1]
    bf16*  wdbf    = (bf16*)(ws + 100663296ull);        //  33,554,432 B
    bf16*  actbf   = (bf16*)(ws + 134217728ull);        // 134,217,728 B
    float* partial = (float*)(ws);                      //  67,108,864 B overlay on hbf/wgubf

    cvt_bf16<<<dim3(4096), 256, 0, stream>>>(h,   hbf,   M_TOK * HIDDEN);
    cvt_bf16<<<dim3(8192), 256, 0, stream>>>(wgu, wgubf, 2 * INTER * HIDDEN);
    cvt_bf16<<<dim3(4096), 256, 0, stream>>>(wd,  wdbf,  HIDDEN * INTER);

    // GEMM1+silu: grid x = INTER/64 = 128 column blocks, y = M_TOK/128 = 64 row blocks
    gemm1_act<<<dim3(128, 64), 256, 0, stream>>>(hbf, wgubf, actbf);

    // GEMM2 split-K=2 interleaved on x: bx&1 = K-half
    gemm2<<<dim3(32, 64), 256, 0, stream>>>(actbf, wdbf, out, partial);

    // out += partial
    add_partial<<<dim3((M_TOK * HIDDEN / 4 + 255) / 256), 256, 0, stream>>>(out, partial, M_TOK * HIDDEN);
}